// Round 2
// baseline (126.253 us; speedup 1.0000x reference)
//
#include <hip/hip_runtime.h>
#include <hip/hip_bf16.h>

// ColorHistogramLoss — fused single-kernel version.
//
// hist[ch][bin] = sum_p exp(-(t_p - c_bin)^2 / 2), t = x*64, c_bin = bin+0.5
// Segmented power-form Gaussian evaluation (8-bin segments):
//   w_{b+k} = w_b * m^k * e^{-k(k-1)/2},  m = e^{u-0.5}, u = t - c_b
// -> 2 exps + ~25 VALU per 8 bins instead of 8 exps (1.7x fewer VALU cycles).
// fp32-range analysis: bins that matter (weight > 1e-8) have segment-start
// distance <= 13.2 -> w_b >= e^-87 (normal). u clamped to 13 for m so that
// m^7 <= ~1e38 stays finite (prevents 0*inf=NaN in the dead far-tail).
//
// Launches: hipMemsetAsync (zero 24*64 hist + counter in ws) + one kernel:
// 768 blocks histogram w/ register accumulators + wave butterfly transpose,
// device atomicAdd into ws hist; last-arriving block (agent-scope ACQ_REL
// counter -> acquire invalidates caches) runs scan/cdf/|diff|/mean tail.

#define BINS 64
#define NCH 12            // B*C
#define HW 65536          // 256*256
#define BPC 32            // blocks per channel-image
#define NBLK (2 * NCH * BPC)                   // 768
#define PIX_PER_BLOCK (HW / BPC)               // 2048
#define THREADS 256
#define PIX_PER_THREAD (PIX_PER_BLOCK / THREADS)  // 8

__device__ __forceinline__ float fast_exp2(float x) {
#if __has_builtin(__builtin_amdgcn_exp2f)
    return __builtin_amdgcn_exp2f(x);
#else
    return exp2f(x);
#endif
}

// K_k = e^{-k(k-1)/2}
#define K2 0.36787944117144233f
#define K3 0.049787068367863944f
#define K4 0.0024787521766663585f
#define K5 4.5399929762484854e-05f
#define K6 3.059023205018258e-07f
#define K7 7.582560427911907e-10f
#define LOG2E 1.4426950408889634f
#define LOG2E_H 0.7213475204444817f

// accumulate one pixel's 64 bin weights into acc[]
__device__ __forceinline__ void eval_pixel(float t, float* acc) {
    #pragma unroll
    for (int s = 0; s < 8; ++s) {
        const float c = (float)(8 * s) + 0.5f;
        float u  = t - c;
        float um = fminf(u, 13.0f);
        float w0 = fast_exp2(-(u * u) * LOG2E_H);          // e^{-u^2/2}
        float m  = fast_exp2(fmaf(um, LOG2E, -0.5f * LOG2E)); // e^{um-0.5}
        float m2 = m * m;
        float m3 = m2 * m;
        float m4 = m2 * m2;
        float m5 = m3 * m2;
        float m6 = m3 * m3;
        float m7 = m4 * m3;
        float p2 = w0 * K2, p3 = w0 * K3, p4 = w0 * K4;
        float p5 = w0 * K5, p6 = w0 * K6, p7 = w0 * K7;
        acc[8 * s + 0] += w0;
        acc[8 * s + 1] = fmaf(w0, m,  acc[8 * s + 1]);
        acc[8 * s + 2] = fmaf(p2, m2, acc[8 * s + 2]);
        acc[8 * s + 3] = fmaf(p3, m3, acc[8 * s + 3]);
        acc[8 * s + 4] = fmaf(p4, m4, acc[8 * s + 4]);
        acc[8 * s + 5] = fmaf(p5, m5, acc[8 * s + 5]);
        acc[8 * s + 6] = fmaf(p6, m6, acc[8 * s + 6]);
        acc[8 * s + 7] = fmaf(p7, m7, acc[8 * s + 7]);
    }
}

__global__ __launch_bounds__(THREADS) void fused_kernel(
        const float* __restrict__ pred,
        const float* __restrict__ target,
        float* __restrict__ hist,          // ws: 24*64 floats, pre-zeroed
        unsigned int* __restrict__ counter, // ws: 1 uint, pre-zeroed
        float* __restrict__ out) {
    const int blk   = blockIdx.x;
    const int ch    = blk / BPC;          // 0..23
    const int chunk = blk % BPC;
    const float* src = (ch < NCH) ? (pred + (size_t)ch * HW)
                                  : (target + (size_t)(ch - NCH) * HW);
    const int base = chunk * PIX_PER_BLOCK + threadIdx.x;

    float acc[BINS];
    #pragma unroll
    for (int j = 0; j < BINS; ++j) acc[j] = 0.0f;

    #pragma unroll 2
    for (int p = 0; p < PIX_PER_THREAD; ++p) {
        float t = src[base + p * THREADS] * 64.0f;
        eval_pixel(t, acc);
    }

    // Wave butterfly transpose-reduce: lane l ends with sum over lanes of acc[l]
    const int lane = threadIdx.x & 63;
    #pragma unroll
    for (int k = 32; k >= 1; k >>= 1) {
        const bool hi = (lane & k) != 0;
        #pragma unroll
        for (int i = 0; i < k; ++i) {
            float keepv = hi ? acc[i + k] : acc[i];
            float sendv = hi ? acc[i] : acc[i + k];
            acc[i] = keepv + __shfl_xor(sendv, k, 64);
        }
    }
    float wave_sum = acc[0];

    __shared__ float bh[BINS];
    __shared__ int is_last;
    if (threadIdx.x < BINS) bh[threadIdx.x] = 0.0f;
    __syncthreads();
    atomicAdd(&bh[lane], wave_sum);
    __syncthreads();
    if (threadIdx.x < BINS)
        atomicAdd(&hist[ch * BINS + threadIdx.x], bh[threadIdx.x]);

    // block-completion counter (release our atomics, acquire others')
    __threadfence();
    if (threadIdx.x == 0) {
        unsigned prev = __hip_atomic_fetch_add(counter, 1u, __ATOMIC_ACQ_REL,
                                               __HIP_MEMORY_SCOPE_AGENT);
        is_last = (prev == NBLK - 1);
    }
    __syncthreads();
    if (!is_last) return;

    // ---- tail: scan/cdf/|diff|/mean, one block (4 waves) ----
    const int w = threadIdx.x >> 6;   // wave 0..3
    float local = 0.0f;
    for (int pch = w; pch < NCH; pch += 4) {
        float ps = hist[pch * BINS + lane];
        float ts = hist[(NCH + pch) * BINS + lane];
        #pragma unroll
        for (int d = 1; d < 64; d <<= 1) {
            float a = __shfl_up(ps, d, 64);
            float b = __shfl_up(ts, d, 64);
            if (lane >= d) { ps += a; ts += b; }
        }
        float ptot = __shfl(ps, 63, 64);
        float ttot = __shfl(ts, 63, 64);
        float dv = fabsf(ps / (ptot + 1e-8f) - ts / (ttot + 1e-8f));
        #pragma unroll
        for (int k = 32; k >= 1; k >>= 1) dv += __shfl_xor(dv, k, 64);
        local += dv;
    }
    __shared__ float wsum[4];
    if (lane == 0) wsum[w] = local;
    __syncthreads();
    if (threadIdx.x == 0)
        out[0] = (wsum[0] + wsum[1] + wsum[2] + wsum[3]) * (1.0f / (NCH * BINS));
}

extern "C" void kernel_launch(void* const* d_in, const int* in_sizes, int n_in,
                              void* d_out, int out_size, void* d_ws, size_t ws_size,
                              hipStream_t stream) {
    const float* pred   = (const float*)d_in[0];
    const float* target = (const float*)d_in[1];
    float* hist = (float*)d_ws;                      // 24*64 floats
    unsigned int* counter = (unsigned int*)((char*)d_ws + NCH * 2 * BINS * 4);
    float* out = (float*)d_out;

    hipMemsetAsync(d_ws, 0, NCH * 2 * BINS * 4 + 4, stream);
    fused_kernel<<<dim3(NBLK), dim3(THREADS), 0, stream>>>(
        pred, target, hist, counter, out);
}